// Round 1
// baseline (188.543 us; speedup 1.0000x reference)
//
#include <hip/hip_runtime.h>

#define NVAL 15

// LTQ forward: out = scale2 * (2/15) * #{i : tf[i] < x*scale1}
// tf reproduces the reference's float32 association exactly:
//   cums = sequential cumsum(a_pos);  tb[i] = s + cums[i-1];  tf[i] = tb[i] + 0.5f*a_pos[i]
__global__ __launch_bounds__(256) void ltq_fwd_kernel(
    const float* __restrict__ x,
    const float* __restrict__ start,
    const float* __restrict__ a,
    const float* __restrict__ scale1,
    const float* __restrict__ scale2,
    float* __restrict__ out,
    int n)
{
    const float s   = start[0];
    const float sc1 = scale1[0];
    const float k   = (float)(2.0 / 15.0) * scale2[0];

    float tf[NVAL];
    float cum = 0.0f;
#pragma unroll
    for (int i = 0; i < NVAL; ++i) {
        float ai = a[i];
        float ap = (ai > 1e-3f) ? ai : 1e-3f;   // jnp.where(a > EPS, a, EPS)
        float tb = s + cum;                     // s + cums[i-1]  (cums[-1] == 0)
        tf[i] = tb + 0.5f * ap;                 // tb + a_pos*0.5
        cum += ap;                              // sequential cumsum, matches np
    }

    const int n4 = n >> 2;
    const float4* __restrict__ x4 = (const float4*)x;
    float4* __restrict__ o4 = (float4*)out;
    const int stride = gridDim.x * blockDim.x;

    for (int idx = blockIdx.x * blockDim.x + threadIdx.x; idx < n4; idx += stride) {
        float4 v = x4[idx];
        float xs0 = v.x * sc1;
        float xs1 = v.y * sc1;
        float xs2 = v.z * sc1;
        float xs3 = v.w * sc1;
        int c0 = 0, c1 = 0, c2 = 0, c3 = 0;
#pragma unroll
        for (int i = 0; i < NVAL; ++i) {
            float t = tf[i];
            c0 += (xs0 > t);   // strict: searchsorted side="left"
            c1 += (xs1 > t);
            c2 += (xs2 > t);
            c3 += (xs3 > t);
        }
        float4 r;
        r.x = k * (float)c0;
        r.y = k * (float)c1;
        r.z = k * (float)c2;
        r.w = k * (float)c3;
        o4[idx] = r;
    }

    // tail (n % 4 != 0 safety; actual N is divisible by 4)
    const int tail_start = n4 << 2;
    for (int idx = tail_start + blockIdx.x * blockDim.x + threadIdx.x; idx < n; idx += stride) {
        float xs = x[idx] * sc1;
        int c = 0;
#pragma unroll
        for (int i = 0; i < NVAL; ++i) c += (xs > tf[i]);
        out[idx] = k * (float)c;
    }
}

extern "C" void kernel_launch(void* const* d_in, const int* in_sizes, int n_in,
                              void* d_out, int out_size, void* d_ws, size_t ws_size,
                              hipStream_t stream) {
    const float* x      = (const float*)d_in[0];
    const float* start  = (const float*)d_in[1];
    const float* a      = (const float*)d_in[2];
    const float* scale1 = (const float*)d_in[3];
    const float* scale2 = (const float*)d_in[4];
    float* out = (float*)d_out;
    const int n = in_sizes[0];

    // 2048 blocks x 256 threads: 8 blocks/CU on 256 CUs -> full 32-wave/CU
    // occupancy, ~12 float4 iterations/thread to amortize threshold setup.
    ltq_fwd_kernel<<<2048, 256, 0, stream>>>(x, start, a, scale1, scale2, out, n);
}